// Round 8
// baseline (107.498 us; speedup 1.0000x reference)
//
#include <hip/hip_runtime.h>

#define TWO_PI 6.28318530717958647692f
// XOR-swizzle for vf2 LDS arrays: nibble0 ^= nibble1.
// Verified conflict-free (b64 floor: 4 lanes/bank-pair) for all access phases
// of the 4096-pt (legacy) and the 16x16x8 2048-pt exchanges.
#define SWZ(i) ((i) ^ (((i) >> 4) & 15))

// 2-wide float vector (maps to v_pk_* f32 ops).
typedef float vf2 __attribute__((ext_vector_type(2)));

__device__ __forceinline__ vf2 mkv(float x, float y) { vf2 r; r.x = x; r.y = y; return r; }
__device__ __forceinline__ vf2 iperp(vf2 z) { return mkv(-z.y, z.x); }   // i*z

// complex product a*b
__device__ __forceinline__ vf2 cmul(vf2 a, vf2 b) {
    return b.x * a + b.y * iperp(a);
}

// z * (wr + i*S*wi), S compile-time sign
template<int SIGN>
__device__ __forceinline__ vf2 twm(vf2 z, float wr, float wi) {
    const float swi = (SIGN > 0) ? wi : -wi;
    return wr * z + swi * iperp(z);
}

// e^{S*i*th} for th in [0, 0.37]: Taylor, err < 2e-7 on this range. (legacy path)
__device__ __forceinline__ vf2 eiw(float th, float S) {
    float t2 = th * th;
    float sn = th * (1.0f + t2 * (-1.0f / 6.0f + t2 * (1.0f / 120.0f)));
    float cs = 1.0f + t2 * (-0.5f + t2 * (1.0f / 24.0f + t2 * (-1.0f / 720.0f)));
    return mkv(cs, S * sn);
}

// e^{+i*th} for th in [0, 0.79]: extended Taylor, err < 4e-7 on this range.
__device__ __forceinline__ vf2 eiw2(float th) {
    float t2 = th * th;
    float sn = th * (1.0f + t2 * (-1.0f / 6.0f + t2 * (1.0f / 120.0f + t2 * (-1.0f / 5040.0f))));
    float cs = 1.0f + t2 * (-0.5f + t2 * (1.0f / 24.0f + t2 * (-1.0f / 720.0f + t2 * (1.0f / 40320.0f))));
    return mkv(cs, sn);
}

// 4-pt butterfly core: inputs a,b,c,d -> ac,as,bd,ib (ib = SIGN*i*(b-d))
template<int SIGN>
__device__ __forceinline__ void bf4core(vf2 a, vf2 b, vf2 c, vf2 d,
                                        vf2& ac, vf2& as, vf2& bd, vf2& ib) {
    ac = a + c; as = a - c;
    bd = b + d;
    vf2 bs = b - d;
    ib = (SIGN > 0) ? iperp(bs) : mkv(bs.y, -bs.x);
}

// 16-point DFT: out[n] = sum_k v[k] * exp(SIGN*2*pi*i*n*k/16), in-place.
// OUTSEL: 0 = all outputs; 1 = only v[4..11] (q=1,2); 2 = only v[0..7] (q=0,1).
template<int SIGN, int OUTSEL>
__device__ __forceinline__ void fft16(vf2* v) {
    vf2 t[16];
    #pragma unroll
    for (int k1 = 0; k1 < 4; ++k1) {           // 4-pt DFT over k2 (stride 4)
        vf2 ac, as, bd, ib;
        bf4core<SIGN>(v[k1], v[k1 + 4], v[k1 + 8], v[k1 + 12], ac, as, bd, ib);
        t[k1 * 4 + 0] = ac + bd;
        t[k1 * 4 + 1] = as + ib;
        t[k1 * 4 + 2] = ac - bd;
        t[k1 * 4 + 3] = as - ib;
    }
    const float c1 = 0.92387953251128674f;     // cos(pi/8)
    const float s1 = 0.38268343236508977f;     // sin(pi/8)
    const float c2 = 0.70710678118654752f;     // cos(pi/4)
    t[5]  = twm<SIGN>(t[5],  c1,  s1);
    t[6]  = twm<SIGN>(t[6],  c2,  c2);
    t[7]  = twm<SIGN>(t[7],  s1,  c1);
    t[9]  = twm<SIGN>(t[9],  c2,  c2);
    t[10] = twm<SIGN>(t[10], 0.f, 1.f);
    t[11] = twm<SIGN>(t[11], -c2, c2);
    t[13] = twm<SIGN>(t[13], s1,  c1);
    t[14] = twm<SIGN>(t[14], -c2, c2);
    t[15] = twm<SIGN>(t[15], -c1, -s1);
    #pragma unroll
    for (int n2 = 0; n2 < 4; ++n2) {           // 4-pt DFT over k1 (stride 4 in t)
        vf2 ac, as, bd, ib;
        bf4core<SIGN>(t[n2], t[4 + n2], t[8 + n2], t[12 + n2], ac, as, bd, ib);
        if (OUTSEL != 1) v[n2 + 0]  = ac + bd;               // q=0
        v[n2 + 4]  = as + ib;                                // q=1 (always needed)
        if (OUTSEL != 2) v[n2 + 8]  = ac - bd;               // q=2
        if (OUTSEL == 0) v[n2 + 12] = as - ib;               // q=3
    }
}

// 4096-pt DFT, 256 threads, radix-16 x3 through swizzled vf2 LDS (32768 B).
// (legacy path, used by kfwd / kfused2)
template<int SIGN, int OUTSEL>
__device__ __forceinline__ void fft4096(vf2* v, vf2* s, int t) {
    const float S = (float)SIGN;
    {
        const int k1 = t & 15, k2 = t >> 4;
        fft16<SIGN, 0>(v);
        vf2 w = eiw(TWO_PI * (float)k2 * (1.0f / 256.0f), S);
        vf2 cur = mkv(1.f, 0.f);
        #pragma unroll
        for (int n3 = 1; n3 < 16; ++n3) {
            cur = cmul(cur, w);
            v[n3] = cmul(v[n3], cur);
        }
        #pragma unroll
        for (int n3 = 0; n3 < 16; ++n3)
            s[SWZ(k2 * 256 + k1 * 16 + n3)] = v[n3];
    }
    __syncthreads();
    {
        const int n3 = t & 15, k1 = t >> 4;
        #pragma unroll
        for (int k2 = 0; k2 < 16; ++k2)
            v[k2] = s[SWZ(k2 * 256 + k1 * 16 + n3)];
        fft16<SIGN, 0>(v);
        vf2 wb  = eiw(TWO_PI * (float)(n3 * k1) * (1.0f / 4096.0f), S);
        vf2 wst = eiw(TWO_PI * (float)k1 * (1.0f / 256.0f), S);
        #pragma unroll
        for (int n2 = 0; n2 < 16; ++n2) {
            v[n2] = cmul(v[n2], wb);
            wb = cmul(wb, wst);
        }
        __syncthreads();
        #pragma unroll
        for (int n2 = 0; n2 < 16; ++n2)
            s[SWZ(k1 * 256 + n2 * 16 + n3)] = v[n2];
    }
    __syncthreads();
    {
        #pragma unroll
        for (int k1 = 0; k1 < 16; ++k1)
            v[k1] = s[SWZ(k1 * 256 + t)];
        fft16<SIGN, OUTSEL>(v);
    }
}

// Stage 1: forward FFT of reflect-padded x. xh[b*2048 + k], k in [0,2048).
__global__ __launch_bounds__(256) void kfwd(const float* __restrict__ x,
                                            vf2* __restrict__ xh) {
    __shared__ vf2 sbuf[4096];
    const int t = threadIdx.x, b = blockIdx.x;
    const float* xr = x + b * 2048;
    vf2 v[16];
    #pragma unroll
    for (int k3 = 0; k3 < 16; ++k3) {
        int j = t + 256 * k3 - 1024;           // reflect pad
        j = (j < 0) ? -j : ((j >= 2048) ? (4094 - j) : j);
        j &= 2047;
        v[k3] = mkv(xr[j], 0.0f);
    }
    fft4096<-1, 2>(v, sbuf, t);
    vf2* xo = xh + b * 2048;
    #pragma unroll
    for (int n1 = 0; n1 < 8; ++n1)
        xo[t + 256 * n1] = v[n1];
}

// Stage 2 (real-split, 16x16x8): one block per (b, scale), 128 threads x 16 elems.
// Real output row Re(ifft4096(Pa*Y)) via even/odd pack: Z[k] = E[k] + i*W4096^k*O[k],
// z = ifft2048(Z), z[n'] = x[2n'] + i*x[2n'+1]. Crop [1024,3072) = z[512,1536).
// E[k] = c*(V[k] + conj(V[2048-k])), O[k] = c*(V[k] - conj(V[2048-k])), V = Pa*Y,
// c = 1/8192 (1/2 Hermitian * 1/2 split * 1/2048 iFFT).
// ifft2048: k = k1 + 8*k2 + 128*k3 (k1<8, k2<16, k3<16); n = n3 + 16*n2 + 256*n1.
//   S1: fft16 over k3 -> n3, twiddle W2048^{n3*t}  (log-depth power tree)
//   S2: fft16 over k2 -> n2, twiddle W128^{k1*n2}  (log-depth power tree)
//   S3: radix-8 over k1 -> n1, pruned to n1 in {2..5} (the crop), reg->global.
//
// NARROW-SCALE EXACT PRUNE (a >= 130): Psih row support is contained in
// [0,250) (f32 underflow analysis of logpsi = 60d + 20(1-e^{3d}) vs lp<-104.7,
// 6-bin margin), so pa[k]==0 for all k in [256,2048] and v[j]==0 for j in
// [2,14). Head does 4 of 16 iterations (8 global loads vs 64); S1's fft16
// degenerates: first radix-4 level on {x,0,0,0}/{0,0,0,x} columns is
// copies/iperp. Exact — only true zeros are skipped. Block-uniform branch.
__global__ __launch_bounds__(128, 4) void kinvr(const float* __restrict__ Psih,
                                                const vf2* __restrict__ xh,
                                                float* __restrict__ out,
                                                long long out_cap) {
    __shared__ vf2 sbuf[2048];
    const int t = threadIdx.x;                 // [0,128)
    // XCD-chunked bijective swizzle: 8192 wgs, 8 XCDs, a-major ordering ->
    // per-XCD working set: Psih slice 512 KB + xh 512 KB (L2-resident).
    const int wg = blockIdx.x;
    const int idx = (wg & 7) * 1024 + (wg >> 3);
    const int a = idx >> 5, b = idx & 31;
    const float* pa = Psih + (size_t)a * 4096;
    const vf2* xr = xh + (size_t)b * 2048;

    // W32^j = e^{i*pi*j/16}, j in [0,16)
    const float W32r[16] = {
        1.0f, 0.98078528040323045f, 0.92387953251128676f, 0.83146961230254524f,
        0.70710678118654752f, 0.55557023301960222f, 0.38268343236508977f, 0.19509032201612827f,
        0.0f, -0.19509032201612827f, -0.38268343236508977f, -0.55557023301960222f,
        -0.70710678118654752f, -0.83146961230254524f, -0.92387953251128676f, -0.98078528040323045f };
    const float W32i[16] = {
        0.0f, 0.19509032201612827f, 0.38268343236508977f, 0.55557023301960222f,
        0.70710678118654752f, 0.83146961230254524f, 0.92387953251128676f, 0.98078528040323045f,
        1.0f, 0.98078528040323045f, 0.92387953251128676f, 0.83146961230254524f,
        0.70710678118654752f, 0.55557023301960222f, 0.38268343236508977f, 0.19509032201612827f };
    const float c = 1.0f / 8192.0f;
    const vf2 wt = eiw2(TWO_PI * (float)t * (1.0f / 4096.0f));   // W4096^t, t<128

    vf2 v[16];
    if (a >= 130) {
        // ---- narrow head: only j in {0,1,14,15} contribute.
        const vf2 w0  = wt;
        const vf2 w1  = cmul(wt, mkv(W32r[1],  W32i[1]));
        const vf2 w14 = cmul(wt, mkv(W32r[14], W32i[14]));
        const vf2 w15 = cmul(wt, mkv(W32r[15], W32i[15]));
        vf2 x0, x1, x14, x15;
        {   // j=0: k=t<128, mirror pa==0
            float p1 = pa[t] * c; vf2 t1 = p1 * xr[t];
            x0 = t1 + iperp(cmul(t1, w0));
        }
        {   // j=1: k=t+128<256, mirror pa==0
            int k = t + 128; float p1 = pa[k] * c; vf2 t1 = p1 * xr[k];
            x1 = t1 + iperp(cmul(t1, w1));
        }
        {   // j=14: pa[k]==0 (k>=1792); mirror m=256-t in (128,256]
            int m = 256 - t; float p2 = pa[m] * c; vf2 Y2 = xr[m & 2047];
            vf2 q2 = mkv(p2 * Y2.x, -p2 * Y2.y);
            x14 = q2 - iperp(cmul(q2, w14));
        }
        {   // j=15: mirror m=128-t in (0,128]
            int m = 128 - t; float p2 = pa[m] * c; vf2 Y2 = xr[m];
            vf2 q2 = mkv(p2 * Y2.x, -p2 * Y2.y);
            x15 = q2 - iperp(cmul(q2, w15));
        }
        // ---- sparse fft16 (SIGN=+1, inputs {0,1,14,15}): first level degenerate.
        vf2 tt[16];
        tt[0] = x0;  tt[1] = x0;  tt[2] = x0;  tt[3] = x0;
        tt[4] = x1;  tt[5] = x1;  tt[6] = x1;  tt[7] = x1;
        tt[8]  = x14; tt[9]  = mkv(x14.y, -x14.x); tt[10] = -x14; tt[11] = iperp(x14);
        tt[12] = x15; tt[13] = mkv(x15.y, -x15.x); tt[14] = -x15; tt[15] = iperp(x15);
        const float c1 = 0.92387953251128674f;
        const float s1 = 0.38268343236508977f;
        const float c2 = 0.70710678118654752f;
        tt[5]  = twm<1>(tt[5],  c1,  s1);
        tt[6]  = twm<1>(tt[6],  c2,  c2);
        tt[7]  = twm<1>(tt[7],  s1,  c1);
        tt[9]  = twm<1>(tt[9],  c2,  c2);
        tt[10] = twm<1>(tt[10], 0.f, 1.f);
        tt[11] = twm<1>(tt[11], -c2, c2);
        tt[13] = twm<1>(tt[13], s1,  c1);
        tt[14] = twm<1>(tt[14], -c2, c2);
        tt[15] = twm<1>(tt[15], -c1, -s1);
        #pragma unroll
        for (int n2 = 0; n2 < 4; ++n2) {
            vf2 ac, as, bd, ib;
            bf4core<1>(tt[n2], tt[4 + n2], tt[8 + n2], tt[12 + n2], ac, as, bd, ib);
            v[n2 + 0]  = ac + bd;
            v[n2 + 4]  = as + ib;
            v[n2 + 8]  = ac - bd;
            v[n2 + 12] = as - ib;
        }
    } else {
        // ---- wide head (full 16 iterations)
        #pragma unroll
        for (int j = 0; j < 16; ++j) {         // k = t + 128*j in [0,2048)
            const int k = t + 128 * j;
            const int m = 2048 - k;            // (0,2048]; Pa[2048]==0 kills m==2048
            float p1 = pa[k] * c;
            float p2 = pa[m] * c;
            vf2 Y1 = xr[k];
            vf2 Y2 = xr[m & 2047];             // mask no-op except m==2048 (p2==0)
            vf2 t1 = p1 * Y1;
            vf2 q2 = mkv(p2 * Y2.x, -p2 * Y2.y);   // (p2,-p2)*Y2
            vf2 E = t1 + q2;
            vf2 O = t1 - q2;
            vf2 w = cmul(wt, mkv(W32r[j], W32i[j]));   // W4096^k
            vf2 ow = cmul(O, w);
            v[j] = E + iperp(ow);              // Z = E + i*(O*w)
        }
        fft16<1, 0>(v);
    }
    // ---- S1 twiddle W2048^{n3*t} (power tree) ; store (k2,k1,n3)
    {
        vf2 w1 = eiw2(TWO_PI * (float)t * (1.0f / 2048.0f));   // t<128 -> th<0.39
        v[1] = cmul(v[1], w1);
        vf2 w2 = cmul(w1, w1); v[2] = cmul(v[2], w2);
        vf2 w3 = cmul(w2, w1); v[3] = cmul(v[3], w3);
        vf2 w4 = cmul(w2, w2); v[4] = cmul(v[4], w4);
        vf2 w5 = cmul(w4, w1); v[5] = cmul(v[5], w5);
        vf2 w6 = cmul(w4, w2); v[6] = cmul(v[6], w6);
        vf2 w7 = cmul(w4, w3); v[7] = cmul(v[7], w7);
        vf2 w8 = cmul(w4, w4); v[8] = cmul(v[8], w8);
        v[9]  = cmul(v[9],  cmul(w8, w1));
        v[10] = cmul(v[10], cmul(w8, w2));
        v[11] = cmul(v[11], cmul(w8, w3));
        v[12] = cmul(v[12], cmul(w8, w4));
        v[13] = cmul(v[13], cmul(w8, w5));
        v[14] = cmul(v[14], cmul(w8, w6));
        v[15] = cmul(v[15], cmul(w8, w7));
        const int k1 = t & 7, k2 = t >> 3;
        const int base = k2 * 128 + k1 * 16;
        #pragma unroll
        for (int n3 = 0; n3 < 16; ++n3) sbuf[SWZ(base + n3)] = v[n3];
    }
    __syncthreads();
    // ---- S2: thread (k1 = t>>4 in [0,8), n3 = t&15); fft16 over k2 -> n2 ;
    //          twiddle W128^{k1*n2} (power tree) ; store (k1,n2,n3)
    {
        const int k1 = t >> 4;
        #pragma unroll
        for (int k2 = 0; k2 < 16; ++k2) v[k2] = sbuf[SWZ(k2 * 128 + t)];   // k1*16+n3 == t
        fft16<1, 0>(v);
        vf2 w1 = eiw2(TWO_PI * (float)k1 * (1.0f / 128.0f));   // k1<8 -> th<0.35
        v[1] = cmul(v[1], w1);
        vf2 w2 = cmul(w1, w1); v[2] = cmul(v[2], w2);
        vf2 w3 = cmul(w2, w1); v[3] = cmul(v[3], w3);
        vf2 w4 = cmul(w2, w2); v[4] = cmul(v[4], w4);
        vf2 w5 = cmul(w4, w1); v[5] = cmul(v[5], w5);
        vf2 w6 = cmul(w4, w2); v[6] = cmul(v[6], w6);
        vf2 w7 = cmul(w4, w3); v[7] = cmul(v[7], w7);
        vf2 w8 = cmul(w4, w4); v[8] = cmul(v[8], w8);
        v[9]  = cmul(v[9],  cmul(w8, w1));
        v[10] = cmul(v[10], cmul(w8, w2));
        v[11] = cmul(v[11], cmul(w8, w3));
        v[12] = cmul(v[12], cmul(w8, w4));
        v[13] = cmul(v[13], cmul(w8, w5));
        v[14] = cmul(v[14], cmul(w8, w6));
        v[15] = cmul(v[15], cmul(w8, w7));
        __syncthreads();                       // all reads done before overwrite
        const int n3 = t & 15;
        const int base = k1 * 256 + n3;
        #pragma unroll
        for (int n2 = 0; n2 < 16; ++n2) sbuf[SWZ(base + n2 * 16)] = v[n2];
    }
    __syncthreads();
    // ---- S3: two pruned radix-8 DFTs over k1, lines p = t and p = t+128.
    // Keep n1 in {2..5}; out vf2 index = p + 256*(n1-2).
    vf2* orow = reinterpret_cast<vf2*>(out) + ((size_t)b * 256 + a) * 1024;
    const long long rowf = ((long long)b * 256 + a) * 2048;      // floats
    const float c2c = 0.70710678118654752f;
    #pragma unroll
    for (int h = 0; h < 2; ++h) {
        const int p = t + 128 * h;
        vf2 u[8];
        #pragma unroll
        for (int k1 = 0; k1 < 8; ++k1) u[k1] = sbuf[SWZ(k1 * 256 + p)];
        vf2 ea, es, eb, ei_;
        bf4core<1>(u[0], u[2], u[4], u[6], ea, es, eb, ei_);
        vf2 A0 = ea + eb, A1 = es + ei_, A2 = ea - eb, A3 = es - ei_;
        vf2 oa, os, ob, oi_;
        bf4core<1>(u[1], u[3], u[5], u[7], oa, os, ob, oi_);
        vf2 B0 = oa + ob, B1 = os + oi_, B2 = oa - ob, B3 = os - oi_;
        B1 = twm<1>(B1, c2c, c2c);             // W8^1
        B2 = iperp(B2);                        // W8^2 = i
        B3 = twm<1>(B3, -c2c, c2c);            // W8^3
        vf2 z2 = A2 + B2;                      // n1 = 2
        vf2 z3 = A3 + B3;                      // n1 = 3
        vf2 z4 = A0 - B0;                      // n1 = 4
        vf2 z5 = A1 - B1;                      // n1 = 5
        if (rowf + 2 * (p + 0)   + 1 < out_cap) orow[p + 0]   = z2;
        if (rowf + 2 * (p + 256) + 1 < out_cap) orow[p + 256] = z3;
        if (rowf + 2 * (p + 512) + 1 < out_cap) orow[p + 512] = z4;
        if (rowf + 2 * (p + 768) + 1 < out_cap) orow[p + 768] = z5;
    }
}

// Fallback if workspace unusable: fused fwd+mul+inv, packed pairs (legacy).
__global__ __launch_bounds__(256) void kfused2(const float* __restrict__ x,
                                               const float* __restrict__ Psih,
                                               float* __restrict__ out,
                                               long long out_cap) {
    __shared__ vf2 sbuf[4096];
    const int t = threadIdx.x;
    const int blk = blockIdx.x;
    const int ap = blk & 127, b = blk >> 7;
    const int a0 = ap * 2;
    const float* xr = x + b * 2048;
    vf2 v[16];
    #pragma unroll
    for (int k3 = 0; k3 < 16; ++k3) {
        int j = t + 256 * k3 - 1024;
        j = (j < 0) ? -j : ((j >= 2048) ? (4094 - j) : j);
        j &= 2047;
        v[k3] = mkv(xr[j], 0.0f);
    }
    fft4096<-1, 0>(v, sbuf, t);
    const float* pa = Psih + (size_t)a0 * 4096;
    const float* pb = pa + 4096;
    const float s = 0.5f / 4096.0f;
    #pragma unroll
    for (int n1 = 0; n1 < 16; ++n1) {
        int k = t + 256 * n1;
        int idx = (k < 2048) ? k : (4096 - k);
        float px = pa[idx] * s, py = pb[idx] * s;
        vf2 X = v[n1];
        v[n1] = mkv(px * X.x - py * X.y, py * X.x + px * X.y);
    }
    __syncthreads();
    fft4096<1, 1>(v, sbuf, t);
    const long long base = ((long long)b * 256 + a0) * 2048;
    #pragma unroll
    for (int n1 = 4; n1 < 12; ++n1) {
        long long oi = base + t + 256 * (n1 - 4);
        if (oi < out_cap) out[oi] = v[n1].x;
        long long oj = oi + 2048;
        if (oj < out_cap) out[oj] = v[n1].y;
    }
}

extern "C" void kernel_launch(void* const* d_in, const int* in_sizes, int n_in,
                              void* d_out, int out_size, void* d_ws, size_t ws_size,
                              hipStream_t stream) {
    const float* x = (const float*)d_in[0];
    const float* Psih = (const float*)d_in[1];
    float* out = (float*)d_out;
    const long long out_cap = (long long)out_size;   // float32 elements
    const size_t xh_bytes = (size_t)32 * 2048 * sizeof(float2);   // 512 KB
    if (ws_size >= xh_bytes && d_ws != nullptr) {
        vf2* xh = (vf2*)d_ws;
        kfwd<<<32, 256, 0, stream>>>(x, xh);
        kinvr<<<8192, 128, 0, stream>>>(Psih, xh, out, out_cap);
    } else {
        kfused2<<<4096, 256, 0, stream>>>(x, Psih, out, out_cap);
    }
}

// Round 12
// 100.386 us; speedup vs baseline: 1.0708x; 1.0708x over previous
//
#include <hip/hip_runtime.h>

#define TWO_PI 6.28318530717958647692f
// XOR-swizzle for vf2 LDS array of 4096: nibble0 ^= nibble1.
// All 4 FFT access phases hit 16 bank-pairs x 4 lanes uniformly (conflict-free b64).
#define SWZ(i) ((i) ^ (((i) >> 4) & 15))

// 2-wide float vector (maps to packed/efficient f32 codegen; measured neutral vs float2).
typedef float vf2 __attribute__((ext_vector_type(2)));

__device__ __forceinline__ vf2 mkv(float x, float y) { vf2 r; r.x = x; r.y = y; return r; }
__device__ __forceinline__ vf2 iperp(vf2 z) { return mkv(-z.y, z.x); }   // i*z

// complex product a*b
__device__ __forceinline__ vf2 cmul(vf2 a, vf2 b) {
    return b.x * a + b.y * iperp(a);
}

// z * (wr + i*S*wi), S compile-time sign
template<int SIGN>
__device__ __forceinline__ vf2 twm(vf2 z, float wr, float wi) {
    const float swi = (SIGN > 0) ? wi : -wi;
    return wr * z + swi * iperp(z);
}

// e^{S*i*th} for th in [0, 0.37]: Taylor, err < 2e-7 on this range.
// (max angle in this FFT decomposition is 2*pi*15/256 = 0.368)
__device__ __forceinline__ vf2 eiw(float th, float S) {
    float t2 = th * th;
    float sn = th * (1.0f + t2 * (-1.0f / 6.0f + t2 * (1.0f / 120.0f)));
    float cs = 1.0f + t2 * (-0.5f + t2 * (1.0f / 24.0f + t2 * (-1.0f / 720.0f)));
    return mkv(cs, S * sn);
}

// 4-pt butterfly core: inputs a,b,c,d -> ac,as,bd,ib (ib = SIGN*i*(b-d))
template<int SIGN>
__device__ __forceinline__ void bf4core(vf2 a, vf2 b, vf2 c, vf2 d,
                                        vf2& ac, vf2& as, vf2& bd, vf2& ib) {
    ac = a + c; as = a - c;
    bd = b + d;
    vf2 bs = b - d;
    ib = (SIGN > 0) ? iperp(bs) : mkv(bs.y, -bs.x);
}

// 16-point DFT: out[n] = sum_k v[k] * exp(SIGN*2*pi*i*n*k/16), in-place.
// OUTSEL: 0 = all outputs; 1 = only v[4..11] (q=1,2); 2 = only v[0..7] (q=0,1).
template<int SIGN, int OUTSEL>
__device__ __forceinline__ void fft16(vf2* v) {
    vf2 t[16];
    #pragma unroll
    for (int k1 = 0; k1 < 4; ++k1) {           // 4-pt DFT over k2 (stride 4)
        vf2 ac, as, bd, ib;
        bf4core<SIGN>(v[k1], v[k1 + 4], v[k1 + 8], v[k1 + 12], ac, as, bd, ib);
        t[k1 * 4 + 0] = ac + bd;
        t[k1 * 4 + 1] = as + ib;
        t[k1 * 4 + 2] = ac - bd;
        t[k1 * 4 + 3] = as - ib;
    }
    const float c1 = 0.92387953251128674f;     // cos(pi/8)
    const float s1 = 0.38268343236508977f;     // sin(pi/8)
    const float c2 = 0.70710678118654752f;     // cos(pi/4)
    t[5]  = twm<SIGN>(t[5],  c1,  s1);
    t[6]  = twm<SIGN>(t[6],  c2,  c2);
    t[7]  = twm<SIGN>(t[7],  s1,  c1);
    t[9]  = twm<SIGN>(t[9],  c2,  c2);
    t[10] = twm<SIGN>(t[10], 0.f, 1.f);
    t[11] = twm<SIGN>(t[11], -c2, c2);
    t[13] = twm<SIGN>(t[13], s1,  c1);
    t[14] = twm<SIGN>(t[14], -c2, c2);
    t[15] = twm<SIGN>(t[15], -c1, -s1);
    #pragma unroll
    for (int n2 = 0; n2 < 4; ++n2) {           // 4-pt DFT over k1 (stride 4 in t)
        vf2 ac, as, bd, ib;
        bf4core<SIGN>(t[n2], t[4 + n2], t[8 + n2], t[12 + n2], ac, as, bd, ib);
        if (OUTSEL != 1) v[n2 + 0]  = ac + bd;               // q=0
        v[n2 + 4]  = as + ib;                                // q=1 (always needed)
        if (OUTSEL != 2) v[n2 + 8]  = ac - bd;               // q=2
        if (OUTSEL == 0) v[n2 + 12] = as - ib;               // q=3
    }
}

// 4096-pt DFT, 256 threads, radix-16 x3 through swizzled vf2 LDS (32768 B).
// Input: v[k3] = x[t + 256*k3]. Output: v[n1] = X[t + 256*n1].
// k = k1 + 16*k2 + 256*k3 ; n = n3 + 16*n2 + 256*n1.
// OUTSEL prunes the final stage only (which n1 are produced).
template<int SIGN, int OUTSEL>
__device__ __forceinline__ void fft4096(vf2* v, vf2* s, int t) {
    const float S = (float)SIGN;
    // ---- step 1: DFT over k3 -> n3 ; twiddle W256^{SIGN*n3*k2}
    {
        const int k1 = t & 15, k2 = t >> 4;
        fft16<SIGN, 0>(v);
        vf2 w = eiw(TWO_PI * (float)k2 * (1.0f / 256.0f), S);
        vf2 cur = mkv(1.f, 0.f);
        #pragma unroll
        for (int n3 = 1; n3 < 16; ++n3) {
            cur = cmul(cur, w);
            v[n3] = cmul(v[n3], cur);
        }
        #pragma unroll
        for (int n3 = 0; n3 < 16; ++n3)
            s[SWZ(k2 * 256 + k1 * 16 + n3)] = v[n3];
    }
    __syncthreads();
    // ---- step 2: DFT over k2 -> n2 ; twiddle W4096^{SIGN*(n3+16*n2)*k1}
    {
        const int n3 = t & 15, k1 = t >> 4;
        #pragma unroll
        for (int k2 = 0; k2 < 16; ++k2)
            v[k2] = s[SWZ(k2 * 256 + k1 * 16 + n3)];
        fft16<SIGN, 0>(v);
        vf2 wb  = eiw(TWO_PI * (float)(n3 * k1) * (1.0f / 4096.0f), S);
        vf2 wst = eiw(TWO_PI * (float)k1 * (1.0f / 256.0f), S);
        #pragma unroll
        for (int n2 = 0; n2 < 16; ++n2) {
            v[n2] = cmul(v[n2], wb);
            wb = cmul(wb, wst);
        }
        __syncthreads();   // all reads done before any in-place overwrite
        #pragma unroll
        for (int n2 = 0; n2 < 16; ++n2)
            s[SWZ(k1 * 256 + n2 * 16 + n3)] = v[n2];
    }
    __syncthreads();
    // ---- step 3: DFT over k1 -> n1 ; thread t = n3 + 16*n2
    {
        #pragma unroll
        for (int k1 = 0; k1 < 16; ++k1)
            v[k1] = s[SWZ(k1 * 256 + t)];      // n2*16 + n3 == t
        fft16<SIGN, OUTSEL>(v);
    }
}

// Stage 1: forward FFT of reflect-padded x. xh[b*2048 + k], k in [0,2048).
// Only n1 in [0,8) needed -> OUTSEL=2 prune.
__global__ __launch_bounds__(256) void kfwd(const float* __restrict__ x,
                                            vf2* __restrict__ xh) {
    __shared__ vf2 sbuf[4096];
    const int t = threadIdx.x, b = blockIdx.x;
    const float* xr = x + b * 2048;
    vf2 v[16];
    #pragma unroll
    for (int k3 = 0; k3 < 16; ++k3) {
        int j = t + 256 * k3 - 1024;           // reflect pad
        j = (j < 0) ? -j : ((j >= 2048) ? (4094 - j) : j);
        j &= 2047;                              // provably no-op; fault-proofing
        v[k3] = mkv(xr[j], 0.0f);
    }
    fft4096<-1, 2>(v, sbuf, t);
    vf2* xo = xh + b * 2048;
    #pragma unroll
    for (int n1 = 0; n1 < 8; ++n1)
        xo[t + 256 * n1] = v[n1];
}

// Stage 2 (packed pairs — the round-1 global-best structure): one block per
// (b, scale-pair). Hermitian-symmetrize the spectra of scales a0=2p, a1=2p+1,
// pack Z = Za + i*Zb, one complex 4096-pt iFFT -> row a0 in .x, a1 in .y.
// Psih[.,0] == Psih[.,2048] == 0, so DC/Nyquist terms are exactly zero.
// Only n1 in [4,12) (crop) needed -> OUTSEL=1 prune.
//
// LATENCY FIX (r8 evidence): occupancy is LDS-capped at 5 blocks/CU
// (20 waves/CU = 5 waves/SIMD) regardless of VGPRs, so VGPRs up to
// floor(512/5)=102 are free. r1's compiler chose 64 (r8's dual-path variant
// collapsed to 52 and got SLOWER -> register-starved ILP). launch_bounds
// min-waves=5 raises the allocator budget to ~102 so the 64 head loads and
// LDS reads stay in flight deeper.
__global__ __launch_bounds__(256, 5) void kinv2(const float* __restrict__ Psih,
                                                const vf2* __restrict__ xh,
                                                float* __restrict__ out,
                                                long long out_cap) {
    __shared__ vf2 sbuf[4096];
    const int t = threadIdx.x;
    // XCD-chunked bijective swizzle: 4096 wgs, 8 XCDs, pair-major ordering ->
    // per-XCD working set: 32 Psih rows (512 KB) + xh (512 KB), L2-resident.
    // (measured: FETCH 3.1 -> 2.0 MB with this on the 8192-wg variant)
    const int blk = blockIdx.x;
    const int idx = (blk & 7) * 512 + (blk >> 3);
    const int ap = idx >> 5, b = idx & 31;
    const int a0 = ap * 2;
    const float* pa = Psih + (size_t)a0 * 4096;
    const float* pb = pa + 4096;
    const vf2* xr = xh + (size_t)b * 2048;
    const float s = 0.5f / 4096.0f;            // Hermitian 1/2 * ifft 1/N
    vf2 v[16];
    #pragma unroll
    for (int k3 = 0; k3 < 8; ++k3) {           // k in [0,2048): Z = s*X*(Pa+iPb)
        int k = t + 256 * k3;
        float px = pa[k] * s, py = pb[k] * s;
        vf2 X = xr[k];
        v[k3] = mkv(px * X.x - py * X.y, py * X.x + px * X.y);
    }
    #pragma unroll
    for (int k3 = 8; k3 < 16; ++k3) {          // k in [2048,4096): Z = s*conj(X[m])*(Pa[m]+iPb[m])
        int m = 4096 - (t + 256 * k3);         // m in [1,2048]
        float px = pa[m] * s, py = pb[m] * s;  // Psih row has 4096 cols; P[2048]==0
        vf2 X = xr[m & 2047];                  // mask no-op except m==2048 (P==0 there)
        v[k3] = mkv(px * X.x + py * X.y, py * X.x - px * X.y);
    }
    fft4096<1, 1>(v, sbuf, t);
    const long long base = ((long long)b * 256 + a0) * 2048;
    #pragma unroll
    for (int n1 = 4; n1 < 12; ++n1) {          // n = t + 256*n1, crop [1024,3072)
        long long oi = base + t + 256 * (n1 - 4);
        if (oi < out_cap) out[oi] = v[n1].x;             // row a0
        long long oj = oi + 2048;
        if (oj < out_cap) out[oj] = v[n1].y;             // row a1
    }
}

// Fallback if workspace unusable: fused fwd+mul+inv, packed pairs.
__global__ __launch_bounds__(256) void kfused2(const float* __restrict__ x,
                                               const float* __restrict__ Psih,
                                               float* __restrict__ out,
                                               long long out_cap) {
    __shared__ vf2 sbuf[4096];
    const int t = threadIdx.x;
    const int blk = blockIdx.x;
    const int ap = blk & 127, b = blk >> 7;
    const int a0 = ap * 2;
    const float* xr = x + b * 2048;
    vf2 v[16];
    #pragma unroll
    for (int k3 = 0; k3 < 16; ++k3) {
        int j = t + 256 * k3 - 1024;
        j = (j < 0) ? -j : ((j >= 2048) ? (4094 - j) : j);
        j &= 2047;
        v[k3] = mkv(xr[j], 0.0f);
    }
    fft4096<-1, 0>(v, sbuf, t);
    const float* pa = Psih + (size_t)a0 * 4096;
    const float* pb = pa + 4096;
    const float s = 0.5f / 4096.0f;
    #pragma unroll
    for (int n1 = 0; n1 < 16; ++n1) {
        int k = t + 256 * n1;
        int idx = (k < 2048) ? k : (4096 - k); // in [0,2048]; P[0]=P[2048]=0
        float px = pa[idx] * s, py = pb[idx] * s;
        vf2 X = v[n1];
        v[n1] = mkv(px * X.x - py * X.y, py * X.x + px * X.y);
    }
    __syncthreads();
    fft4096<1, 1>(v, sbuf, t);
    const long long base = ((long long)b * 256 + a0) * 2048;
    #pragma unroll
    for (int n1 = 4; n1 < 12; ++n1) {
        long long oi = base + t + 256 * (n1 - 4);
        if (oi < out_cap) out[oi] = v[n1].x;
        long long oj = oi + 2048;
        if (oj < out_cap) out[oj] = v[n1].y;
    }
}

extern "C" void kernel_launch(void* const* d_in, const int* in_sizes, int n_in,
                              void* d_out, int out_size, void* d_ws, size_t ws_size,
                              hipStream_t stream) {
    const float* x = (const float*)d_in[0];
    const float* Psih = (const float*)d_in[1];
    float* out = (float*)d_out;
    const long long out_cap = (long long)out_size;   // float32 elements
    const size_t xh_bytes = (size_t)32 * 2048 * sizeof(float) * 2;   // 512 KB
    if (ws_size >= xh_bytes && d_ws != nullptr) {
        vf2* xh = (vf2*)d_ws;
        kfwd<<<32, 256, 0, stream>>>(x, xh);
        kinv2<<<4096, 256, 0, stream>>>(Psih, xh, out, out_cap);
    } else {
        kfused2<<<4096, 256, 0, stream>>>(x, Psih, out, out_cap);
    }
}